// Round 14
// baseline (38.377 us; speedup 1.0000x reference)
//
#include <hip/hip_runtime.h>

#define IMGD 28
#define OUTD 26
#define NCLS 10
#define NIMG 64
#define SLAB 15                 // staged input rows per block
#define SLABF4 105              // float4 per image slab (15*28/4)
#define TOTF4 (NIMG * SLABF4)   // 6720
#define RPADH 32                // halves per padded row (28 data + 4 pad)
#define IMGU 61                 // 16B units per image (15*4 + 1 pad, odd -> bank-clean)
#define THREADS 512
#define LDSTRIDE 11

typedef float v2f __attribute__((ext_vector_type(2)));

// read strip halves [OFF, OFF+WID+2) of staged row r (unit base 4r+U0), image=lane
template<int WID, int NRD, int OFF>
__device__ __forceinline__ void read_rowh(const unsigned short* ldsh, int lane,
                                          int r4, int U0, float* R)
{
    const uint4* b4 = (const uint4*)ldsh;
    const int base = lane * IMGU + r4 + U0;   // quad=(5*lane+c)%8: all 8 -> conflict-free
    unsigned int w[4 * NRD];
    uint4 a = b4[base];
    w[0] = a.x; w[1] = a.y; w[2] = a.z; w[3] = a.w;
    if constexpr (NRD == 2) {
        uint4 b = b4[base + 1];
        w[4] = b.x; w[5] = b.y; w[6] = b.z; w[7] = b.w;
    }
#pragma unroll
    for (int i = 0; i < WID + 2; ++i) {
        const int hh = OFF + i;               // compile-time after unroll
        unsigned int word = w[hh >> 1];
        unsigned short u = (hh & 1) ? (unsigned short)(word >> 16)
                                    : (unsigned short)(word & 0xffffu);
        R[i] = (float)__builtin_bit_cast(_Float16, u);
    }
}

// one output row: conv3x3 (tree) + relu + rank-1 GEMM update, W wave-uniform
template<int WID>
__device__ __forceinline__ void conv_row(const float* X, const float* Y, const float* Z,
                                         const float (&kk)[9],
                                         const float* __restrict__ wr, v2f* acc)
{
#pragma unroll
    for (int c = 0; c < WID; ++c) {
        float p0 = fmaf(X[c], kk[0], X[c+1] * kk[1]);
        p0 = fmaf(X[c+2], kk[2], p0);
        float p1 = fmaf(Y[c], kk[3], Y[c+1] * kk[4]);
        p1 = fmaf(Y[c+2], kk[5], p1);
        float p2 = fmaf(Z[c], kk[6], Z[c+1] * kk[7]);
        p2 = fmaf(Z[c+2], kk[8], p2);
        float v = fmaxf((p0 + p1) + p2, 0.0f);
        const float* w = wr + c * NCLS;       // wave-uniform -> s_load
#pragma unroll
        for (int p = 0; p < 5; ++p) {
            v2f wv2 = *(const v2f*)(w + 2 * p);
            v2f vv; vv[0] = v; vv[1] = v;
            acc[p] += vv * wv2;               // v_pk_fma_f32
        }
    }
}

// 13 output rows of one col strip, rolling 3-row register window, each staged
// row read exactly once, NO synchronization (all data resident after 1 barrier)
template<int WID, int NRD, int OFF>
__device__ __forceinline__ void strip13(const unsigned short* ldsh, int lane,
                                        int U0, int c0, int wrow0,
                                        const float (&kk)[9],
                                        const float* __restrict__ Wp, v2f* acc)
{
    float A[WID+2], Bv[WID+2], C[WID+2];
    read_rowh<WID,NRD,OFF>(ldsh, lane, 0, U0, A);
    read_rowh<WID,NRD,OFF>(ldsh, lane, 4, U0, Bv);
#define OUTR(j, X, Y, Z, rin)                                            \
    read_rowh<WID,NRD,OFF>(ldsh, lane, 4*(rin), U0, Z);                  \
    conv_row<WID>(X, Y, Z, kk,                                           \
                  Wp + ((size_t)(wrow0 + (j)) * OUTD + c0) * NCLS, acc);
    OUTR(0,  A,  Bv, C,  2)
    OUTR(1,  Bv, C,  A,  3)
    OUTR(2,  C,  A,  Bv, 4)
    OUTR(3,  A,  Bv, C,  5)
    OUTR(4,  Bv, C,  A,  6)
    OUTR(5,  C,  A,  Bv, 7)
    OUTR(6,  A,  Bv, C,  8)
    OUTR(7,  Bv, C,  A,  9)
    OUTR(8,  C,  A,  Bv, 10)
    OUTR(9,  A,  Bv, C,  11)
    OUTR(10, Bv, C,  A,  12)
    OUTR(11, C,  A,  Bv, 13)
    OUTR(12, A,  Bv, C,  14)
#undef OUTR
}

__global__ __launch_bounds__(THREADS, 4) void fused_conv_relu_fc(
    const float* __restrict__ x,      // [B, 784]
    const float* __restrict__ cw,     // [9]
    const float* __restrict__ Wp,     // [676, 10]
    const float* __restrict__ bp,     // [10]
    float* __restrict__ out,          // [B, 10] (pre-zeroed; atomicAdd)
    int B)
{
    __shared__ __align__(16) unsigned short ldsh[NIMG * IMGU * 8];  // 62464 B

    const int t    = threadIdx.x;
    const int lane = t & 63;
    const int wv   = __builtin_amdgcn_readfirstlane((int)(t >> 6)); // 0..7
    const int grp  = blockIdx.x >> 1;
    const int h    = blockIdx.x & 1;              // row half
    const int img_base = grp * NIMG;
    const int r0 = h * 13;                        // input rows r0..r0+14

    // ---- stage whole slab: coalesced fp32 reads -> f16 LDS, ONE barrier ----
    float4 v[14];
#pragma unroll
    for (int it = 0; it < 14; ++it) {             // all loads issued before use
        int F = it * THREADS + t; if (F >= TOTF4) F = TOTF4 - 1;
        int g = F / SLABF4;                       // image within group
        int s = F - g * SLABF4;                   // float4 within 15-row slab
        int gi = img_base + g; if (gi >= B) gi = B - 1;
        v[it] = *(const float4*)(x + (size_t)gi * (IMGD*IMGD) + r0 * IMGD + s * 4);
    }
#pragma unroll
    for (int it = 0; it < 14; ++it) {
        int F0 = it * THREADS + t;
        int F = F0 >= TOTF4 ? TOTF4 - 1 : F0;
        int g = F / SLABF4;
        int s = F - g * SLABF4;
        int r = s / 7;                            // row within slab (7 float4/row)
        int c4 = s - r * 7;
        ushort4 o;
        o.x = __builtin_bit_cast(unsigned short, (_Float16)v[it].x);
        o.y = __builtin_bit_cast(unsigned short, (_Float16)v[it].y);
        o.z = __builtin_bit_cast(unsigned short, (_Float16)v[it].z);
        o.w = __builtin_bit_cast(unsigned short, (_Float16)v[it].w);
        if (F0 < TOTF4)
            *(ushort4*)&ldsh[g * (IMGU * 8) + r * RPADH + c4 * 4] = o;
    }
    __syncthreads();                              // the ONLY staging barrier

    // ---- compute: 7 col strips (6 x w4 + 1 x w2), wave 7 idle ----
    float kk[9];
#pragma unroll
    for (int i = 0; i < 9; ++i) kk[i] = cw[i];    // uniform -> SGPRs

    v2f acc[5];
#pragma unroll
    for (int p = 0; p < 5; ++p) { acc[p][0] = 0.0f; acc[p][1] = 0.0f; }

    if      (wv == 0) strip13<4,1,0>(ldsh, lane, 0, 0,  r0, kk, Wp, acc);
    else if (wv == 1) strip13<4,2,4>(ldsh, lane, 0, 4,  r0, kk, Wp, acc);
    else if (wv == 2) strip13<4,1,0>(ldsh, lane, 1, 8,  r0, kk, Wp, acc);
    else if (wv == 3) strip13<4,2,4>(ldsh, lane, 1, 12, r0, kk, Wp, acc);
    else if (wv == 4) strip13<4,1,0>(ldsh, lane, 2, 16, r0, kk, Wp, acc);
    else if (wv == 5) strip13<4,2,4>(ldsh, lane, 2, 20, r0, kk, Wp, acc);
    else if (wv == 6) strip13<2,1,0>(ldsh, lane, 3, 24, r0, kk, Wp, acc);

    __syncthreads();                              // all LDS reads done

    // ---- combine 8 wave-partials via LDS overlay, atomicAdd row-halves ----
    float* part = (float*)ldsh;                   // 8*64*11*4 = 22528 B overlay
    float* myp = &part[(wv * 64 + lane) * LDSTRIDE];
#pragma unroll
    for (int p = 0; p < 5; ++p) { myp[2*p] = acc[p][0]; myp[2*p+1] = acc[p][1]; }
    __syncthreads();

    // FIX (R13 bug): 640 outputs > 512 threads -> strided loop, not single if
    for (int o = t; o < NIMG * NCLS; o += THREADS) {
        const int im = o / NCLS;
        const int c  = o - im * NCLS;
        float s = (h == 0) ? bp[c] : 0.0f;        // bias added once
#pragma unroll
        for (int w2 = 0; w2 < 8; ++w2)
            s += part[(w2 * 64 + im) * LDSTRIDE + c];
        if (img_base + im < B)                    // 2 commutative contributors
            atomicAdd(&out[(size_t)(img_base + im) * NCLS + c], s);
    }
}

extern "C" void kernel_launch(void* const* d_in, const int* in_sizes, int n_in,
                              void* d_out, int out_size, void* d_ws, size_t ws_size,
                              hipStream_t stream) {
    const float* x  = (const float*)d_in[0];
    const float* cw = (const float*)d_in[1];
    const float* Wp = (const float*)d_in[2];
    const float* bp = (const float*)d_in[3];
    float* out = (float*)d_out;

    const int B = in_sizes[0] / (IMGD * IMGD);    // 32768
    const int ngrp = (B + NIMG - 1) / NIMG;       // 512 groups x 2 row-halves

    hipMemsetAsync(d_out, 0, (size_t)out_size * sizeof(float), stream);
    fused_conv_relu_fc<<<ngrp * 2, THREADS, 0, stream>>>(x, cw, Wp, bp, out, B);
}

// Round 15
// 32.663 us; speedup vs baseline: 1.1750x; 1.1750x over previous
//
#include <hip/hip_runtime.h>

#define IMGD 28
#define OUTD 26
#define NCLS 10
#define NIMG 64
#define UPB 35                       // float4 units per image per 5-row band (5*28/4), odd -> bank-clean
#define UPB_T 21                     // tail band: 3 rows (3*28/4), odd -> bank-clean
#define BWORDS (NIMG * UPB * 4)      // 8960 floats = 35840 B per buffer
#define NBAND 6
#define THREADS 1024
#define LDSTRIDE 11

typedef float v2f __attribute__((ext_vector_type(2)));

__device__ __forceinline__ void gload_lds16(const float* gp, float* lp) {
    __builtin_amdgcn_global_load_lds(
        (const __attribute__((address_space(1))) void*)gp,
        (__attribute__((address_space(3))) void*)lp, 16, 0, 0);
}

// Stage one disjoint band (UNITS float4-units per image, rows r0..) of 64
// images. LDS: [img][unit] linear, stride UNITS (odd) -> ds_read_b128 at
// (UNITS*lane + u) % 8 covers all 8 bank-quads: conflict-free.
// Global source: lane-consecutive units within each image's contiguous
// band block -> coalesced (~16 lines per wave-instr).
template<int UNITS>
__device__ __forceinline__ void stage_band(const float* __restrict__ x,
                                           int img_base, int B, int r0,
                                           float* buf, int wv, int lane)
{
#pragma unroll
    for (int it = 0; it < 3; ++it) {
        const int fw = it * 16 + wv;             // wave-uniform chunk id
        if (fw < UNITS) {
            const int f = fw * 64 + lane;        // flat unit index
            const int g = f / UNITS;             // image 0..63 (constexpr div)
            const int s = f - g * UNITS;         // unit within band
            int gi = img_base + g; if (gi >= B) gi = B - 1;
            const float* gp = x + (size_t)gi * (IMGD * IMGD) + r0 * IMGD + s * 4;
            gload_lds16(gp, buf + fw * 256);     // uniform base + lane*16B
        }
    }
}

// read NU float4 units (band row br, unit col u0) of image `lane`, layout stride STRIDE
template<int NU, int STRIDE>
__device__ __forceinline__ void read_row(const float* buf, int lane, int br, int u0,
                                         float* dst)
{
    const float4* b4 = (const float4*)buf;
#pragma unroll
    for (int u = 0; u < NU; ++u) {
        float4 a = b4[lane * STRIDE + br * 7 + u0 + u];
        dst[4*u+0] = a.x; dst[4*u+1] = a.y; dst[4*u+2] = a.z; dst[4*u+3] = a.w;
    }
}

// one output row: conv3x3 (tree) + relu + rank-1 GEMM update, W wave-uniform
template<int WID, int OFF>
__device__ __forceinline__ void conv_row(const float* X, const float* Y, const float* Z,
                                         const float (&kk)[9],
                                         const float* __restrict__ wr, v2f* acc)
{
#pragma unroll
    for (int c = 0; c < WID; ++c) {
        float p0 = fmaf(X[OFF+c], kk[0], X[OFF+c+1] * kk[1]);
        p0 = fmaf(X[OFF+c+2], kk[2], p0);
        float p1 = fmaf(Y[OFF+c], kk[3], Y[OFF+c+1] * kk[4]);
        p1 = fmaf(Y[OFF+c+2], kk[5], p1);
        float p2 = fmaf(Z[OFF+c], kk[6], Z[OFF+c+1] * kk[7]);
        p2 = fmaf(Z[OFF+c+2], kk[8], p2);
        float v = fmaxf((p0 + p1) + p2, 0.0f);
        const float* w = wr + c * NCLS;          // wave-uniform -> s_load
#pragma unroll
        for (int p = 0; p < 5; ++p) {
            v2f wv2 = *(const v2f*)(w + 2 * p);
            v2f vv; vv[0] = v; vv[1] = v;
            acc[p] += vv * wv2;                  // v_pk_fma_f32
        }
    }
}

// Round-5 proven schedule (depth-2, counted vmcnt, double barrier), 5-row bands:
// bands 0..4 = rows 5k..5k+4 (35 units), band 5 = rows 25..27 (21 units).
// rg0: within rows 5k,5k+1,5k+2 (rolling 3-row window of the 5 staged rows).
// rg1: straddle rows 5k-2,5k-1 from 2-row register halo (band k-1 rows 3,4).
template<int WID, int NU, int OFF>
__device__ __forceinline__ void run_all(
    const float* __restrict__ x, int img_base, int B,
    float* lds0, int wv, int lane, int rg, int u0, int c0,
    const float* __restrict__ cw, const float* __restrict__ Wp, v2f* acc)
{
    float kk[9];
#pragma unroll
    for (int i = 0; i < 9; ++i) kk[i] = cw[i];   // uniform -> SGPRs

    float S0[4 * NU], S1[4 * NU];                // halo rows (rg=1 only)

    stage_band<UPB>(x, img_base, B, 0, lds0,          wv, lane);
    stage_band<UPB>(x, img_base, B, 5, lds0 + BWORDS, wv, lane);

    for (int k = 0; k < NBAND - 1; ++k) {        // k = 0..4
        // wait band k; leave band k+1 in flight (counted by this wave's share)
        if (k == NBAND - 2) {                    // band 5 (21 units) in flight
            if (wv < 5) asm volatile("s_waitcnt vmcnt(2)" ::: "memory");
            else        asm volatile("s_waitcnt vmcnt(1)" ::: "memory");
        } else {                                 // 35-unit band in flight
            if (wv < 3) asm volatile("s_waitcnt vmcnt(3)" ::: "memory");
            else        asm volatile("s_waitcnt vmcnt(2)" ::: "memory");
        }
        __builtin_amdgcn_s_barrier();            // band k landed for all waves

        const float* buf = lds0 + (k & 1) * BWORDS;

        if (rg == 0) {
            // outputs 5k,5k+1,5k+2 from band rows 0..4 (rolling window)
            float Ra[4*NU], Rb[4*NU], Rc[4*NU], Rd[4*NU], Re[4*NU];
            read_row<NU, UPB>(buf, lane, 0, u0, Ra);
            read_row<NU, UPB>(buf, lane, 1, u0, Rb);
            read_row<NU, UPB>(buf, lane, 2, u0, Rc);
            conv_row<WID, OFF>(Ra, Rb, Rc, kk,
                               Wp + ((size_t)(5 * k) * OUTD + c0) * NCLS, acc);
            read_row<NU, UPB>(buf, lane, 3, u0, Rd);
            conv_row<WID, OFF>(Rb, Rc, Rd, kk,
                               Wp + ((size_t)(5 * k + 1) * OUTD + c0) * NCLS, acc);
            read_row<NU, UPB>(buf, lane, 4, u0, Re);
            conv_row<WID, OFF>(Rc, Rd, Re, kk,
                               Wp + ((size_t)(5 * k + 2) * OUTD + c0) * NCLS, acc);
        } else {
            if (k > 0) {
                // straddle outputs 5k-2,5k-1: halo rows + band k rows 0,1
                float Ta[4*NU], Tb[4*NU];
                read_row<NU, UPB>(buf, lane, 0, u0, Ta);
                read_row<NU, UPB>(buf, lane, 1, u0, Tb);
                conv_row<WID, OFF>(S0, S1, Ta, kk,
                                   Wp + ((size_t)(5 * k - 2) * OUTD + c0) * NCLS, acc);
                conv_row<WID, OFF>(S1, Ta, Tb, kk,
                                   Wp + ((size_t)(5 * k - 1) * OUTD + c0) * NCLS, acc);
            }
            read_row<NU, UPB>(buf, lane, 3, u0, S0);   // halo = band k rows 3,4
            read_row<NU, UPB>(buf, lane, 4, u0, S1);
        }

        if (k <= NBAND - 3) {                    // stage band k+2 into buf[k&1]
            asm volatile("" ::: "memory");
            __builtin_amdgcn_s_barrier();        // all reads of buf[k&1] done
            asm volatile("" ::: "memory");
            if (k == 3)
                stage_band<UPB_T>(x, img_base, B, 25, lds0 + (k & 1) * BWORDS, wv, lane);
            else
                stage_band<UPB>(x, img_base, B, 5 * (k + 2), lds0 + (k & 1) * BWORDS, wv, lane);
        }
    }

    // tail: band 5 (rows 25..27, stride 21) in buf1
    asm volatile("s_waitcnt vmcnt(0)" ::: "memory");
    __builtin_amdgcn_s_barrier();
    const float* buf = lds0 + BWORDS;
    if (rg == 0) {
        float Ta[4*NU], Tb[4*NU], Tc[4*NU];
        read_row<NU, UPB_T>(buf, lane, 0, u0, Ta);
        read_row<NU, UPB_T>(buf, lane, 1, u0, Tb);
        read_row<NU, UPB_T>(buf, lane, 2, u0, Tc);
        conv_row<WID, OFF>(Ta, Tb, Tc, kk,
                           Wp + ((size_t)25 * OUTD + c0) * NCLS, acc);
    } else {
        float Ta[4*NU], Tb[4*NU];
        read_row<NU, UPB_T>(buf, lane, 0, u0, Ta);
        read_row<NU, UPB_T>(buf, lane, 1, u0, Tb);
        conv_row<WID, OFF>(S0, S1, Ta, kk,
                           Wp + ((size_t)23 * OUTD + c0) * NCLS, acc);
        conv_row<WID, OFF>(S1, Ta, Tb, kk,
                           Wp + ((size_t)24 * OUTD + c0) * NCLS, acc);
    }
}

__global__ __launch_bounds__(THREADS, 8) void fused_conv_relu_fc(
    const float* __restrict__ x,      // [B, 784]
    const float* __restrict__ cw,     // [9]
    const float* __restrict__ Wp,     // [676, 10]
    const float* __restrict__ bp,     // [10]
    float* __restrict__ out,          // [B, 10]
    int B)
{
    __shared__ float lds[2 * BWORDS];            // 71680 B -> 2 blocks/CU

    const int lane = threadIdx.x & 63;
    const int wv   = __builtin_amdgcn_readfirstlane((int)(threadIdx.x >> 6));
    const int rg   = wv >> 3;                    // 0: within-band, 1: straddle
    const int cs   = wv & 7;                     // col strip
    const int img_base = blockIdx.x * NIMG;

    v2f acc[5];
#pragma unroll
    for (int p = 0; p < 5; ++p) { acc[p][0] = 0.0f; acc[p][1] = 0.0f; }

    // strips: 5 x width-4 + 3 x width-2 (identical barrier sequences)
    if      (cs < 5)  run_all<4,2,0>(x, img_base, B, lds, wv, lane, rg, cs, 4*cs, cw, Wp, acc);
    else if (cs == 5) run_all<2,1,0>(x, img_base, B, lds, wv, lane, rg, 5,  20,   cw, Wp, acc);
    else if (cs == 6) run_all<2,2,2>(x, img_base, B, lds, wv, lane, rg, 5,  22,   cw, Wp, acc);
    else              run_all<2,1,0>(x, img_base, B, lds, wv, lane, rg, 6,  24,   cw, Wp, acc);

    __syncthreads();                             // all band-5 reads done before overlay

    // partials -> LDS overlay (stride 11: 2 lanes/bank -> free)
    float* part = lds;                           // 16*64*11*4 = 45056 B < 71680
    float* myp = &part[(wv * 64 + lane) * LDSTRIDE];
#pragma unroll
    for (int p = 0; p < 5; ++p) { myp[2*p] = acc[p][0]; myp[2*p+1] = acc[p][1]; }
    __syncthreads();

    // combine 16 partials + bias; coalesced 640-float store per block
    const int o = threadIdx.x;
    if (o < NIMG * NCLS) {
        const int im = o / NCLS;
        const int c  = o - im * NCLS;
        float s = bp[c];
#pragma unroll
        for (int w2 = 0; w2 < 16; ++w2)
            s += part[(w2 * 64 + im) * LDSTRIDE + c];
        if (img_base + im < B)
            out[(size_t)(img_base + im) * NCLS + c] = s;
    }
}

extern "C" void kernel_launch(void* const* d_in, const int* in_sizes, int n_in,
                              void* d_out, int out_size, void* d_ws, size_t ws_size,
                              hipStream_t stream) {
    const float* x  = (const float*)d_in[0];
    const float* cw = (const float*)d_in[1];
    const float* Wp = (const float*)d_in[2];
    const float* bp = (const float*)d_in[3];
    float* out = (float*)d_out;

    const int B = in_sizes[0] / (IMGD * IMGD);   // 32768
    const int grid = (B + NIMG - 1) / NIMG;      // 512 blocks x 16 waves

    fused_conv_relu_fc<<<grid, THREADS, 0, stream>>>(x, cw, Wp, bp, out, B);
}